// Round 3
// baseline (387.546 us; speedup 1.0000x reference)
//
#include <hip/hip_runtime.h>

typedef unsigned short u16;
typedef unsigned int u32;
typedef _Float16 f16x8 __attribute__((ext_vector_type(8)));
typedef float f32x4 __attribute__((ext_vector_type(4)));

__device__ __forceinline__ u16 f2h(float f) {
    _Float16 h = (_Float16)f;
    return __builtin_bit_cast(u16, h);
}

// ---------------- conv1d(256->128,k=3,pad=1) + ReLU -> hT[b][t][c] fp32 ----------------
__global__ void conv_kernel(const float* __restrict__ x, const float* __restrict__ w,
                            const float* __restrict__ bias, float* __restrict__ hT) {
    int t = blockIdx.x, b = blockIdx.y, co = threadIdx.x;  // 128 threads
    float acc = bias[co];
    const float* xb = x + b * 256 * 128;
    const float* wr = w + co * 768;
    for (int ci = 0; ci < 256; ++ci) {
        float x0 = (t >= 1)   ? xb[ci * 128 + t - 1] : 0.f;
        float x1 =              xb[ci * 128 + t];
        float x2 = (t < 127) ? xb[ci * 128 + t + 1] : 0.f;
        acc += x0 * wr[ci * 3 + 0] + x1 * wr[ci * 3 + 1] + x2 * wr[ci * 3 + 2];
    }
    hT[b * 16384 + t * 128 + co] = fmaxf(acc, 0.f);
}

// ---------------- cell -> (d,m) table (valid cells enumerated d-major) ----------------
__global__ void table_kernel(int* __restrict__ tab) {
    for (int cell = threadIdx.x; cell < 8256; cell += blockDim.x) {
        int off = 0, d = 0;
        while (d < 128) { int w = 128 - d; if (cell < off + w) break; off += w; ++d; }
        tab[cell] = (d << 8) | (cell - off);
    }
}

// ---------------- fp32 -> fp16 convert ----------------
__global__ void cvt_kernel(const float* __restrict__ src, u16* __restrict__ dst, int n) {
    int i = blockIdx.x * blockDim.x + threadIdx.x;
    if (i < n) dst[i] = f2h(src[i]);
}

// ---------------- constant output vector for invalid cells ----------------
__global__ void c0_kernel(const float* __restrict__ w2, const float* __restrict__ b3,
                          const float* __restrict__ b2, float* __restrict__ c0) {
    int o2 = threadIdx.x;
    if (o2 >= 128) return;
    float s = b2[o2];
    for (int o = 0; o < 512; ++o) s += w2[o2 * 512 + o] * fmaxf(b3[o], 0.f);
    c0[o2] = fmaxf(s, 0.f);
}

// ---------------- fill invalid cells with c0 ----------------
__global__ void fill_kernel(const float* __restrict__ c0, float* __restrict__ out) {
    int d = blockIdx.x, b = blockIdx.y;
    if (d == 0) return;
    int cnt = d, total = 128 * cnt;
    for (int idx = threadIdx.x; idx < total; idx += blockDim.x) {
        int o2 = idx / cnt, m = 128 - cnt + (idx % cnt);
        out[((size_t)b << 21) + ((size_t)o2 << 14) + (d << 7) + m] = c0[o2];
    }
}

// ---------------- build MBt[(b,cell)][(c,n)] fp16 from hT + closed-form taps ----------------
// MBt row-major: row = global col (b*8256+cell), 4096 K-elements (c*32+n) contiguous.
// CRITICAL: tap positions s must match numpy's double arithmetic BIT-FOR-BIT.
// The bin-weight function has a cliff at s == -1.0 exactly (weight 1 vs 0); numpy
// computes s with mul-then-add (two roundings). FP contraction to fma (one rounding)
// can land on the wrong side of the cliff -> contract(off) here.
__global__ __launch_bounds__(256) void mb_build(const float* __restrict__ hT,
                                                const int* __restrict__ tab,
                                                u16* __restrict__ MBt) {
#pragma clang fp contract(off)
    __shared__ float hs[128][129];  // +1 pad: avoids 32-way bank conflict on column reads
    int c0g = blockIdx.x * 8;       // 8 global cols per block; 8256%8==0 so b is uniform
    int b = (c0g >= 8256) ? 1 : 0;
    const float* hb = hT + b * 16384;
    for (int idx = threadIdx.x; idx < 16384; idx += 256)
        hs[idx >> 7][idx & 127] = hb[idx];
    __syncthreads();
    int n = threadIdx.x & 31, cb = threadIdx.x >> 5;
    for (int cc = 0; cc < 8; ++cc) {
        int colg = c0g + cc;
        int cell = colg - b * 8256;
        int dm = tab[cell];
        int d = dm >> 8, m = dm & 255;
        double xm = m - (d + 1) * 0.5;          // exact (half-integer)
        double step = (2 * d + 1) / 95.0;       // single rounding, same as numpy
        float tw[6]; int tt[6];
#pragma unroll
        for (int j = 0; j < 3; ++j) {
            double p = step * (double)(3 * n + j);  // rounding #1 (matches plen_sample*ii)
            double s = xm + p;                       // rounding #2 (matches seg_xmin + ...)
            double tr = trunc(s);          // matches python modf int-part (toward zero)
            double dec = s - tr;           // signed fraction, matches modf
            int dn = (int)tr;
            int up = (int)ceil(s);
            bool vdn = (dn >= 0 && dn <= 127);
            bool vup = (up >= 0 && up <= 127);
            tt[2 * j]     = vdn ? dn : 0;
            tw[2 * j]     = vdn ? (float)((1.0 - dec) * (1.0 / 3.0)) : 0.f;
            tt[2 * j + 1] = vup ? up : 0;
            tw[2 * j + 1] = vup ? (float)(dec * (1.0 / 3.0)) : 0.f;
        }
        u16 vals[16];
#pragma unroll
        for (int k = 0; k < 16; ++k) {
            int c = cb + (k << 3);
            float v = 0.f;
#pragma unroll
            for (int i = 0; i < 6; ++i) v = fmaf(tw[i], hs[tt[i]][c], v);
            vals[k] = f2h(v);
        }
        size_t base = (size_t)colg * 4096;
#pragma unroll
        for (int k = 0; k < 16; ++k)
            MBt[base + threadIdx.x + (k << 8)] = vals[k];  // row r = (cb+8k)*32+n = tid+256k
    }
}

// ---------------- fp16 MFMA GEMM, both operands K-contiguous (A[M][K], B^T[N][K]) ----------------
// EPI 1: C[o][col] -> m3T[col*512+o] = fp16(relu(acc + bias[o]))
// EPI 2: C[col][o2] -> out[b][o2][d][m] = relu(acc + bias[o2]) for valid cols
template <int EPI>
__global__ __launch_bounds__(256) void gemm_bt(const u16* __restrict__ A, const u16* __restrict__ B,
                                               int M, int N, int K,
                                               const float* __restrict__ bias,
                                               u16* __restrict__ outHf, float* __restrict__ outF,
                                               const int* __restrict__ tab) {
    __shared__ alignas(16) u16 As[128 * 64];
    __shared__ alignas(16) u16 Bs[128 * 64];
    const int tid = threadIdx.x;
    const int lane = tid & 63, wave = tid >> 6;
    const int m0 = blockIdx.y * 128, n0 = blockIdx.x * 128;
    const int wr = wave & 1, wc = wave >> 1;
    const int fr = lane & 15, fk = (lane >> 4) * 16;  // frag row, frag k-chunk (bytes)
    f32x4 acc[4][4] = {};

    for (int kt = 0; kt < K; kt += 64) {
#pragma unroll
        for (int i = 0; i < 4; ++i) {
            int off = i * 4096 + wave * 1024 + lane * 16;  // byte in 16KB tile
            int row = off >> 7, colb = off & 127;
            const u16* ga = A + (size_t)(m0 + row) * K + kt + (colb >> 1);
            const u16* gb = B + (size_t)(n0 + row) * K + kt + (colb >> 1);
            __builtin_amdgcn_global_load_lds(
                (const __attribute__((address_space(1))) void*)ga,
                (__attribute__((address_space(3))) void*)((char*)As + i * 4096 + wave * 1024),
                16, 0, 0);
            __builtin_amdgcn_global_load_lds(
                (const __attribute__((address_space(1))) void*)gb,
                (__attribute__((address_space(3))) void*)((char*)Bs + i * 4096 + wave * 1024),
                16, 0, 0);
        }
        __syncthreads();
#pragma unroll
        for (int kk = 0; kk < 2; ++kk) {
            f16x8 af[4], bfr[4];
            const int kb = kk * 64 + fk;
#pragma unroll
            for (int mf = 0; mf < 4; ++mf) {
                int row = wr * 64 + mf * 16 + fr;
                af[mf] = *(const f16x8*)((const char*)As + row * 128 + kb);
            }
#pragma unroll
            for (int nf = 0; nf < 4; ++nf) {
                int row = wc * 64 + nf * 16 + fr;
                bfr[nf] = *(const f16x8*)((const char*)Bs + row * 128 + kb);
            }
#pragma unroll
            for (int mf = 0; mf < 4; ++mf)
#pragma unroll
                for (int nf = 0; nf < 4; ++nf)
                    acc[mf][nf] = __builtin_amdgcn_mfma_f32_16x16x32_f16(
                        af[mf], bfr[nf], acc[mf][nf], 0, 0, 0);
        }
        __syncthreads();
    }

    if constexpr (EPI == 1) {
#pragma unroll
        for (int nf = 0; nf < 4; ++nf) {
            int col = n0 + wc * 64 + nf * 16 + fr;
#pragma unroll
            for (int mf = 0; mf < 4; ++mf) {
                int ob = m0 + wr * 64 + mf * 16 + ((lane >> 4) << 2);
                f32x4 v = acc[mf][nf];
                unsigned long long pw = 0;
#pragma unroll
                for (int r = 0; r < 4; ++r) {
                    float z = fmaxf(v[r] + bias[ob + r], 0.f);
                    pw |= (unsigned long long)f2h(z) << (16 * r);
                }
                *(unsigned long long*)(outHf + (size_t)col * 512 + ob) = pw;
            }
        }
    } else {
#pragma unroll
        for (int mf = 0; mf < 4; ++mf) {
            int rbase = m0 + wr * 64 + mf * 16 + ((lane >> 4) << 2);
#pragma unroll
            for (int nf = 0; nf < 4; ++nf) {
                int o2 = n0 + wc * 64 + nf * 16 + fr;
                f32x4 v = acc[mf][nf];
#pragma unroll
                for (int r = 0; r < 4; ++r) {
                    int colg = rbase + r;
                    if (colg < 16512) {
                        int b = (colg >= 8256) ? 1 : 0;
                        int cell = colg - b * 8256;
                        int dm = tab[cell];
                        float z = fmaxf(v[r] + bias[o2], 0.f);
                        outF[((size_t)b << 21) + ((size_t)o2 << 14) + ((dm >> 8) << 7) + (dm & 255)] = z;
                    }
                }
            }
        }
    }
}

// ws layout (bytes):
//   0        hT      fp32 [2][128][128]            131072
//   131072   W3h     fp16 [512][4096]              4194304
//   4325376  W2h     fp16 [128][512]               131072
//   4456448  c0      fp32 [128]                    512
//   4456960  tab     int  [8256] (alloc 16512)     66048
//   4523008  m3T     fp16 [16640][512]             17039360
//   21562368 MBt     fp16 [16640][4096]            136314880   -> total ~158 MB
extern "C" void kernel_launch(void* const* d_in, const int* in_sizes, int n_in,
                              void* d_out, int out_size, void* d_ws, size_t ws_size,
                              hipStream_t stream) {
    const float* x     = (const float*)d_in[0];
    const float* w_red = (const float*)d_in[1];
    const float* b_red = (const float*)d_in[2];
    const float* w3d   = (const float*)d_in[3];
    const float* b3d   = (const float*)d_in[4];
    const float* w2d   = (const float*)d_in[5];
    const float* b2d   = (const float*)d_in[6];
    float* out = (float*)d_out;

    char* ws = (char*)d_ws;
    float* hT  = (float*)(ws + 0);
    u16*   W3h = (u16*)(ws + 131072);
    u16*   W2h = (u16*)(ws + 4325376);
    float* c0  = (float*)(ws + 4456448);
    int*   tab = (int*)(ws + 4456960);
    u16*   m3T = (u16*)(ws + 4523008);
    u16*   MBt = (u16*)(ws + 21562368);

    conv_kernel<<<dim3(128, 2), 128, 0, stream>>>(x, w_red, b_red, hT);
    table_kernel<<<1, 256, 0, stream>>>(tab);
    cvt_kernel<<<8192, 256, 0, stream>>>(w3d, W3h, 2097152);
    cvt_kernel<<<256, 256, 0, stream>>>(w2d, W2h, 65536);
    c0_kernel<<<1, 128, 0, stream>>>(w2d, b3d, b2d, c0);
    mb_build<<<2064, 256, 0, stream>>>(hT, tab, MBt);
    gemm_bt<1><<<dim3(130, 4), 256, 0, stream>>>(W3h, MBt, 512, 16640, 4096, b3d, m3T, nullptr, nullptr);
    gemm_bt<2><<<dim3(1, 130), 256, 0, stream>>>(m3T, W2h, 16640, 128, 512, b2d, nullptr, out, tab);
    fill_kernel<<<dim3(128, 2), 256, 0, stream>>>(c0, out);
}

// Round 4
// 336.329 us; speedup vs baseline: 1.1523x; 1.1523x over previous
//
#include <hip/hip_runtime.h>

typedef unsigned short u16;
typedef unsigned int u32;
typedef unsigned long long u64;
typedef _Float16 f16x8 __attribute__((ext_vector_type(8)));
typedef float f32x4 __attribute__((ext_vector_type(4)));

__device__ __forceinline__ u16 f2h(float f) {
    _Float16 h = (_Float16)f;
    return __builtin_bit_cast(u16, h);
}

// ---------------- conv1d(256->128,k=3,pad=1) + ReLU -> hT[b][t][c] fp32 ----------------
__global__ void conv_kernel(const float* __restrict__ x, const float* __restrict__ w,
                            const float* __restrict__ bias, float* __restrict__ hT) {
    int t = blockIdx.x, b = blockIdx.y, co = threadIdx.x;  // 128 threads
    float acc = bias[co];
    const float* xb = x + b * 256 * 128;
    const float* wr = w + co * 768;
    for (int ci = 0; ci < 256; ++ci) {
        float x0 = (t >= 1)   ? xb[ci * 128 + t - 1] : 0.f;
        float x1 =              xb[ci * 128 + t];
        float x2 = (t < 127) ? xb[ci * 128 + t + 1] : 0.f;
        acc += x0 * wr[ci * 3 + 0] + x1 * wr[ci * 3 + 1] + x2 * wr[ci * 3 + 2];
    }
    hT[b * 16384 + t * 128 + co] = fmaxf(acc, 0.f);
}

// ---------------- cell -> (d,m) table (valid cells enumerated d-major) ----------------
__global__ void table_kernel(int* __restrict__ tab) {
    for (int cell = threadIdx.x; cell < 8256; cell += blockDim.x) {
        int off = 0, d = 0;
        while (d < 128) { int w = 128 - d; if (cell < off + w) break; off += w; ++d; }
        tab[cell] = (d << 8) | (cell - off);
    }
}

// ---------------- fp32 -> fp16 convert ----------------
__global__ void cvt_kernel(const float* __restrict__ src, u16* __restrict__ dst, int n) {
    int i = blockIdx.x * blockDim.x + threadIdx.x;
    if (i < n) dst[i] = f2h(src[i]);
}

// ---------------- constant output vector for invalid cells ----------------
__global__ void c0_kernel(const float* __restrict__ w2, const float* __restrict__ b3,
                          const float* __restrict__ b2, float* __restrict__ c0) {
    int o2 = threadIdx.x;
    if (o2 >= 128) return;
    float s = b2[o2];
    for (int o = 0; o < 512; ++o) s += w2[o2 * 512 + o] * fmaxf(b3[o], 0.f);
    c0[o2] = fmaxf(s, 0.f);
}

// ---------------- fill invalid cells with c0 ----------------
__global__ void fill_kernel(const float* __restrict__ c0, float* __restrict__ out) {
    int d = blockIdx.x, b = blockIdx.y;
    if (d == 0) return;
    int cnt = d, total = 128 * cnt;
    for (int idx = threadIdx.x; idx < total; idx += blockDim.x) {
        int o2 = idx / cnt, m = 128 - cnt + (idx % cnt);
        out[((size_t)b << 21) + ((size_t)o2 << 14) + (d << 7) + m] = c0[o2];
    }
}

// ---------------- build MBt[(b,cell)][(c,n)] fp16 from hT + closed-form taps ----------------
// Tap positions must match numpy's double arithmetic bit-for-bit (cliff at s==-1.0):
// mul-then-add with contract(off), never fma.
__global__ __launch_bounds__(256) void mb_build(const float* __restrict__ hT,
                                                const int* __restrict__ tab,
                                                u16* __restrict__ MBt) {
#pragma clang fp contract(off)
    __shared__ float hs[128][129];
    int c0g = blockIdx.x * 8;
    int b = (c0g >= 8256) ? 1 : 0;
    const float* hb = hT + b * 16384;
    for (int idx = threadIdx.x; idx < 16384; idx += 256)
        hs[idx >> 7][idx & 127] = hb[idx];
    __syncthreads();
    int n = threadIdx.x & 31, cb = threadIdx.x >> 5;
    for (int cc = 0; cc < 8; ++cc) {
        int colg = c0g + cc;
        int cell = colg - b * 8256;
        int dm = tab[cell];
        int d = dm >> 8, m = dm & 255;
        double xm = m - (d + 1) * 0.5;
        double step = (2 * d + 1) / 95.0;
        float tw[6]; int tt[6];
#pragma unroll
        for (int j = 0; j < 3; ++j) {
            double p = step * (double)(3 * n + j);
            double s = xm + p;
            double tr = trunc(s);
            double dec = s - tr;
            int dn = (int)tr;
            int up = (int)ceil(s);
            bool vdn = (dn >= 0 && dn <= 127);
            bool vup = (up >= 0 && up <= 127);
            tt[2 * j]     = vdn ? dn : 0;
            tw[2 * j]     = vdn ? (float)((1.0 - dec) * (1.0 / 3.0)) : 0.f;
            tt[2 * j + 1] = vup ? up : 0;
            tw[2 * j + 1] = vup ? (float)(dec * (1.0 / 3.0)) : 0.f;
        }
        u16 vals[16];
#pragma unroll
        for (int k = 0; k < 16; ++k) {
            int c = cb + (k << 3);
            float v = 0.f;
#pragma unroll
            for (int i = 0; i < 6; ++i) v = fmaf(tw[i], hs[tt[i]][c], v);
            vals[k] = f2h(v);
        }
        size_t base = (size_t)colg * 4096;
#pragma unroll
        for (int k = 0; k < 16; ++k)
            MBt[base + threadIdx.x + (k << 8)] = vals[k];
    }
}

// ---------------- fused mega-GEMM ----------------
// Block p owns 64 cells (one n-panel) of batch b = p/129; computes
//   m3[512][64] = relu(W3h[512][4096] . MBt_panel^T + b3)   (BM=512, BN=64, BK=64)
//   out[128][64] = relu(W2h[128][512] . m3 + b2)            (epilogue MFMA from LDS)
// B (MBt, 136 MB) is streamed exactly once across the grid.
// 4 waves; wave tile for GEMM1: 128m x 64n (acc 8x4 f32x4 = 128 VGPR).
__global__ __launch_bounds__(256, 2) void mega_kernel(
        const u16* __restrict__ W3h, const u16* __restrict__ MBt,
        const u16* __restrict__ W2h,
        const float* __restrict__ b3, const float* __restrict__ b2,
        const int* __restrict__ tab, float* __restrict__ out) {
    __shared__ alignas(16) char lds[73728];       // As 64KB + Bs 8KB; m3s reuses
    char* As = lds;                                // [512][64] fp16, row pitch 128 B
    char* Bs = lds + 65536;                        // [64][64]  fp16, row pitch 128 B

    const int tid = threadIdx.x;
    const int lane = tid & 63, wr = tid >> 6;      // wave index 0..3
    const int fr = lane & 15, fk = (lane >> 4) * 16;  // frag row, frag k-chunk (bytes)

    const int p = blockIdx.x;
    const int b = (p >= 129) ? 1 : 0;
    const int cell0 = (p - 129 * b) * 64;
    const size_t brow0 = (size_t)b * 8256 + cell0;  // first MBt row of this panel

    f32x4 acc[8][4] = {};

    for (int kt = 0; kt < 4096; kt += 64) {
#pragma unroll
        for (int i = 0; i < 16; ++i) {              // stage As: 512x64 fp16 = 64 KB
            int off = i * 4096 + tid * 16;
            int row = off >> 7, colb = off & 127;
            const u16* ga = W3h + (size_t)row * 4096 + kt + (colb >> 1);
            __builtin_amdgcn_global_load_lds(
                (const __attribute__((address_space(1))) void*)ga,
                (__attribute__((address_space(3))) void*)(As + off), 16, 0, 0);
        }
#pragma unroll
        for (int i = 0; i < 2; ++i) {               // stage Bs: 64x64 fp16 = 8 KB
            int off = i * 4096 + tid * 16;
            int row = off >> 7, colb = off & 127;
            const u16* gb = MBt + (brow0 + row) * 4096 + kt + (colb >> 1);
            __builtin_amdgcn_global_load_lds(
                (const __attribute__((address_space(1))) void*)gb,
                (__attribute__((address_space(3))) void*)(Bs + off), 16, 0, 0);
        }
        __syncthreads();
#pragma unroll
        for (int kk = 0; kk < 2; ++kk) {
            const int kb = kk * 64 + fk;
            f16x8 bfr[4];
#pragma unroll
            for (int nf = 0; nf < 4; ++nf)
                bfr[nf] = *(const f16x8*)(Bs + (nf * 16 + fr) * 128 + kb);
#pragma unroll
            for (int mf = 0; mf < 8; ++mf) {
                f16x8 af = *(const f16x8*)(As + (wr * 128 + mf * 16 + fr) * 128 + kb);
#pragma unroll
                for (int nf = 0; nf < 4; ++nf)
                    acc[mf][nf] = __builtin_amdgcn_mfma_f32_16x16x32_f16(
                        af, bfr[nf], acc[mf][nf], 0, 0, 0);
            }
        }
        __syncthreads();
    }

    // ---- epilogue 1: m3s[cell][o] fp16, row pitch 520 elems (1040 B: 2-way banks, free)
    u16* m3s = (u16*)lds;
#pragma unroll
    for (int mf = 0; mf < 8; ++mf) {
        int o = wr * 128 + mf * 16 + ((lane >> 4) << 2);
#pragma unroll
        for (int nf = 0; nf < 4; ++nf) {
            int cell = nf * 16 + fr;
            f32x4 v = acc[mf][nf];
            u64 pw = 0;
#pragma unroll
            for (int r = 0; r < 4; ++r) {
                float z = fmaxf(v[r] + b3[o + r], 0.f);
                pw |= (u64)f2h(z) << (16 * r);
            }
            *(u64*)(m3s + cell * 520 + o) = pw;
        }
    }
    __syncthreads();

    // ---- epilogue 2: out-tile = relu(W2 . m3 + b2); A-frags straight from global (L2)
    f32x4 acc2[2][4] = {};
#pragma unroll
    for (int kk = 0; kk < 16; ++kk) {
        f16x8 a2[2];
#pragma unroll
        for (int mf = 0; mf < 2; ++mf) {
            int o2 = wr * 32 + mf * 16 + fr;
            a2[mf] = *(const f16x8*)(W2h + o2 * 512 + kk * 32 + ((lane >> 4) << 3));
        }
        f16x8 bfr[4];
#pragma unroll
        for (int nf = 0; nf < 4; ++nf) {
            int cell = nf * 16 + fr;
            bfr[nf] = *(const f16x8*)(m3s + cell * 520 + kk * 32 + ((lane >> 4) << 3));
        }
#pragma unroll
        for (int mf = 0; mf < 2; ++mf)
#pragma unroll
            for (int nf = 0; nf < 4; ++nf)
                acc2[mf][nf] = __builtin_amdgcn_mfma_f32_16x16x32_f16(
                    a2[mf], bfr[nf], acc2[mf][nf], 0, 0, 0);
    }

#pragma unroll
    for (int mf = 0; mf < 2; ++mf) {
        int o2b = wr * 32 + mf * 16 + ((lane >> 4) << 2);
#pragma unroll
        for (int nf = 0; nf < 4; ++nf) {
            int cell = cell0 + nf * 16 + fr;
            int dm = tab[cell];
            size_t base = ((size_t)b << 21) + (size_t)((dm >> 8) << 7) + (dm & 255);
            f32x4 v = acc2[mf][nf];
#pragma unroll
            for (int r = 0; r < 4; ++r) {
                float z = fmaxf(v[r] + b2[o2b + r], 0.f);
                out[base + ((size_t)(o2b + r) << 14)] = z;
            }
        }
    }
}

// ws layout (bytes):
//   0        hT      fp32 [2][128][128]            131072
//   131072   W3h     fp16 [512][4096]              4194304
//   4325376  W2h     fp16 [128][512]               131072
//   4456448  c0      fp32 [128]                    512
//   4456960  tab     int  [8256] (alloc 16512)     66048
//   21562368 MBt     fp16 [16512][4096]            135266304
extern "C" void kernel_launch(void* const* d_in, const int* in_sizes, int n_in,
                              void* d_out, int out_size, void* d_ws, size_t ws_size,
                              hipStream_t stream) {
    const float* x     = (const float*)d_in[0];
    const float* w_red = (const float*)d_in[1];
    const float* b_red = (const float*)d_in[2];
    const float* w3d   = (const float*)d_in[3];
    const float* b3d   = (const float*)d_in[4];
    const float* w2d   = (const float*)d_in[5];
    const float* b2d   = (const float*)d_in[6];
    float* out = (float*)d_out;

    char* ws = (char*)d_ws;
    float* hT  = (float*)(ws + 0);
    u16*   W3h = (u16*)(ws + 131072);
    u16*   W2h = (u16*)(ws + 4325376);
    float* c0  = (float*)(ws + 4456448);
    int*   tab = (int*)(ws + 4456960);
    u16*   MBt = (u16*)(ws + 21562368);

    conv_kernel<<<dim3(128, 2), 128, 0, stream>>>(x, w_red, b_red, hT);
    table_kernel<<<1, 256, 0, stream>>>(tab);
    cvt_kernel<<<8192, 256, 0, stream>>>(w3d, W3h, 2097152);
    cvt_kernel<<<256, 256, 0, stream>>>(w2d, W2h, 65536);
    c0_kernel<<<1, 128, 0, stream>>>(w2d, b3d, b2d, c0);
    mb_build<<<2064, 256, 0, stream>>>(hT, tab, MBt);
    mega_kernel<<<258, 256, 0, stream>>>(W3h, MBt, W2h, b3d, b2d, tab, out);
    fill_kernel<<<dim3(128, 2), 256, 0, stream>>>(c0, out);
}

// Round 5
// 335.039 us; speedup vs baseline: 1.1567x; 1.0039x over previous
//
#include <hip/hip_runtime.h>

typedef unsigned short u16;
typedef unsigned int u32;
typedef unsigned long long u64;
typedef _Float16 f16x8 __attribute__((ext_vector_type(8)));
typedef float f32x4 __attribute__((ext_vector_type(4)));

__device__ __forceinline__ u16 f2h(float f) {
    _Float16 h = (_Float16)f;
    return __builtin_bit_cast(u16, h);
}

// ---------------- conv1d(256->128,k=3,pad=1) + ReLU -> hT[b][t][c] fp32 ----------------
__global__ void conv_kernel(const float* __restrict__ x, const float* __restrict__ w,
                            const float* __restrict__ bias, float* __restrict__ hT) {
    int t = blockIdx.x, b = blockIdx.y, co = threadIdx.x;  // 128 threads
    float acc = bias[co];
    const float* xb = x + b * 256 * 128;
    const float* wr = w + co * 768;
    for (int ci = 0; ci < 256; ++ci) {
        float x0 = (t >= 1)   ? xb[ci * 128 + t - 1] : 0.f;
        float x1 =              xb[ci * 128 + t];
        float x2 = (t < 127) ? xb[ci * 128 + t + 1] : 0.f;
        acc += x0 * wr[ci * 3 + 0] + x1 * wr[ci * 3 + 1] + x2 * wr[ci * 3 + 2];
    }
    hT[b * 16384 + t * 128 + co] = fmaxf(acc, 0.f);
}

// ---------------- prep: blocks 0..255 cvt W2 -> fp16; block 256: tab + c0 ----------------
__global__ void prep_kernel(const float* __restrict__ w2d, const float* __restrict__ b3,
                            const float* __restrict__ b2, int* __restrict__ tab,
                            u16* __restrict__ W2h, float* __restrict__ c0) {
    if (blockIdx.x < 256) {
        int i = blockIdx.x * 256 + threadIdx.x;
        W2h[i] = f2h(w2d[i]);
        return;
    }
    for (int cell = threadIdx.x; cell < 8256; cell += 256) {
        int off = 0, d = 0;
        while (d < 128) { int w = 128 - d; if (cell < off + w) break; off += w; ++d; }
        tab[cell] = (d << 8) | (cell - off);
    }
    if (threadIdx.x < 128) {
        int o2 = threadIdx.x;
        float s = b2[o2];
        for (int o = 0; o < 512; ++o) s += w2d[o2 * 512 + o] * fmaxf(b3[o], 0.f);
        c0[o2] = fmaxf(s, 0.f);
    }
}

// ---------------- fp32 -> fp16 convert (W3) ----------------
__global__ void cvt_kernel(const float* __restrict__ src, u16* __restrict__ dst, int n) {
    int i = blockIdx.x * blockDim.x + threadIdx.x;
    if (i < n) dst[i] = f2h(src[i]);
}

// ---------------- fill invalid cells with c0 ----------------
__global__ void fill_kernel(const float* __restrict__ c0, float* __restrict__ out) {
    int d = blockIdx.x, b = blockIdx.y;
    if (d == 0) return;
    int cnt = d, total = 128 * cnt;
    for (int idx = threadIdx.x; idx < total; idx += blockDim.x) {
        int o2 = idx / cnt, m = 128 - cnt + (idx % cnt);
        out[((size_t)b << 21) + ((size_t)o2 << 14) + (d << 7) + m] = c0[o2];
    }
}

// ---------------- build MBt[(b,cell)][(c,n)] fp16 from hT + closed-form taps ----------------
// Tap positions must match numpy's double arithmetic bit-for-bit (cliff at s==-1.0):
// mul-then-add with contract(off), never fma.
__global__ __launch_bounds__(256) void mb_build(const float* __restrict__ hT,
                                                const int* __restrict__ tab,
                                                u16* __restrict__ MBt) {
#pragma clang fp contract(off)
    __shared__ float hs[128][129];
    int c0g = blockIdx.x * 8;
    int b = (c0g >= 8256) ? 1 : 0;
    const float* hb = hT + b * 16384;
    for (int idx = threadIdx.x; idx < 16384; idx += 256)
        hs[idx >> 7][idx & 127] = hb[idx];
    __syncthreads();
    int n = threadIdx.x & 31, cb = threadIdx.x >> 5;
    for (int cc = 0; cc < 8; ++cc) {
        int colg = c0g + cc;
        int cell = colg - b * 8256;
        int dm = tab[cell];
        int d = dm >> 8, m = dm & 255;
        double xm = m - (d + 1) * 0.5;
        double step = (2 * d + 1) / 95.0;
        float tw[6]; int tt[6];
#pragma unroll
        for (int j = 0; j < 3; ++j) {
            double p = step * (double)(3 * n + j);
            double s = xm + p;
            double tr = trunc(s);
            double dec = s - tr;
            int dn = (int)tr;
            int up = (int)ceil(s);
            bool vdn = (dn >= 0 && dn <= 127);
            bool vup = (up >= 0 && up <= 127);
            tt[2 * j]     = vdn ? dn : 0;
            tw[2 * j]     = vdn ? (float)((1.0 - dec) * (1.0 / 3.0)) : 0.f;
            tt[2 * j + 1] = vup ? up : 0;
            tw[2 * j + 1] = vup ? (float)(dec * (1.0 / 3.0)) : 0.f;
        }
        u16 vals[16];
#pragma unroll
        for (int k = 0; k < 16; ++k) {
            int c = cb + (k << 3);
            float v = 0.f;
#pragma unroll
            for (int i = 0; i < 6; ++i) v = fmaf(tw[i], hs[tt[i]][c], v);
            vals[k] = f2h(v);
        }
        size_t base = (size_t)colg * 4096;
#pragma unroll
        for (int k = 0; k < 16; ++k)
            MBt[base + threadIdx.x + (k << 8)] = vals[k];
    }
}

// ---------------- fused mega-GEMM v2: dbuf 2-phase pipeline + XOR swizzle ----------------
// Block p: 64-cell n-panel of batch b. BM=512(all M), BN=64, BK=64. 8 waves, wave tile 64x64.
// LDS: As dbuf 2x64KB @0, Bs dbuf 2x8KB @131072 (144 KB). Swizzle: colb ^= (row&7)<<4,
// applied to BOTH the global_load_lds source col and the frag-read col (involution).
__global__ __launch_bounds__(512, 2) void mega_kernel(
        const u16* __restrict__ W3h, const u16* __restrict__ MBt,
        const u16* __restrict__ W2h,
        const float* __restrict__ b3, const float* __restrict__ b2,
        const int* __restrict__ tab, float* __restrict__ out) {
    __shared__ alignas(16) char lds[147456];

    const int tid = threadIdx.x;
    const int lane = tid & 63, wv = tid >> 6;      // wave 0..7
    const int fr = lane & 15, fq = lane >> 4;      // frag row, quad
    const int swz = (fr & 7) << 4;                 // read-side XOR (row&7 == fr&7)

    const int p = blockIdx.x;
    const int b = (p >= 129) ? 1 : 0;
    const int cell0 = (p - 129 * b) * 64;
    const size_t brow0 = (size_t)b * 8256 + cell0;

    f32x4 acc[4][4] = {};

    auto stage = [&](int buf, int kt) {
        char* A = lds + buf * 65536;
        char* B = lds + 131072 + buf * 8192;
#pragma unroll
        for (int i = 0; i < 8; ++i) {               // A: 512x64 fp16 = 64 KB
            int off = i * 8192 + tid * 16;
            int row = off >> 7, colb = off & 127;
            int scol = colb ^ ((row & 7) << 4);     // pre-swizzled global source
            const u16* ga = W3h + (size_t)row * 4096 + kt + (scol >> 1);
            __builtin_amdgcn_global_load_lds(
                (const __attribute__((address_space(1))) void*)ga,
                (__attribute__((address_space(3))) void*)(A + off), 16, 0, 0);
        }
        {                                           // B: 64x64 fp16 = 8 KB
            int off = tid * 16;
            int row = off >> 7, colb = off & 127;
            int scol = colb ^ ((row & 7) << 4);
            const u16* gb = MBt + (brow0 + row) * 4096 + kt + (scol >> 1);
            __builtin_amdgcn_global_load_lds(
                (const __attribute__((address_space(1))) void*)gb,
                (__attribute__((address_space(3))) void*)(B + off), 16, 0, 0);
        }
    };

    stage(0, 0);
    __syncthreads();                                // drain prologue
    for (int t = 0; t < 64; ++t) {
        int cur = t & 1;
        if (t < 63) stage(cur ^ 1, (t + 1) << 6);   // prefetch next tile
        const char* A = lds + cur * 65536;
        const char* B = lds + 131072 + cur * 8192;
#pragma unroll
        for (int kk = 0; kk < 2; ++kk) {
            const int kb = kk * 64 + (fq << 4);
            const int ekb = kb ^ swz;               // swizzled read col
            f16x8 af[4], bfr[4];
#pragma unroll
            for (int nf = 0; nf < 4; ++nf)
                bfr[nf] = *(const f16x8*)(B + (nf * 16 + fr) * 128 + ekb);
#pragma unroll
            for (int mf = 0; mf < 4; ++mf)
                af[mf] = *(const f16x8*)(A + (wv * 64 + mf * 16 + fr) * 128 + ekb);
#pragma unroll
            for (int mf = 0; mf < 4; ++mf)
#pragma unroll
                for (int nf = 0; nf < 4; ++nf)
                    acc[mf][nf] = __builtin_amdgcn_mfma_f32_16x16x32_f16(
                        af[mf], bfr[nf], acc[mf][nf], 0, 0, 0);
        }
        __syncthreads();                            // drains prefetch (issued ~full iter ago)
    }

    // ---- epilogue 1: m3s[cell][o], pitch 520 fp16 (1040 B -> 2-way banks, free)
    u16* m3s = (u16*)lds;
#pragma unroll
    for (int mf = 0; mf < 4; ++mf) {
        int ob = wv * 64 + mf * 16 + (fq << 2);
#pragma unroll
        for (int nf = 0; nf < 4; ++nf) {
            int cell = nf * 16 + fr;
            f32x4 v = acc[mf][nf];
            u64 pw = 0;
#pragma unroll
            for (int r = 0; r < 4; ++r) {
                float z = fmaxf(v[r] + b3[ob + r], 0.f);
                pw |= (u64)f2h(z) << (16 * r);
            }
            *(u64*)(m3s + cell * 520 + ob) = pw;
        }
    }
    __syncthreads();

    // ---- epilogue 2: out = relu(W2 . m3 + b2); each wave owns 16 o2-rows
    f32x4 acc2[4] = {};
#pragma unroll
    for (int kk = 0; kk < 16; ++kk) {
        f16x8 a2 = *(const f16x8*)(W2h + (wv * 16 + fr) * 512 + kk * 32 + (fq << 3));
#pragma unroll
        for (int nf = 0; nf < 4; ++nf) {
            f16x8 bfr = *(const f16x8*)(m3s + (nf * 16 + fr) * 520 + kk * 32 + (fq << 3));
            acc2[nf] = __builtin_amdgcn_mfma_f32_16x16x32_f16(a2, bfr, acc2[nf], 0, 0, 0);
        }
    }
#pragma unroll
    for (int nf = 0; nf < 4; ++nf) {
        int cell = cell0 + nf * 16 + fr;
        int dm = tab[cell];
        size_t base = ((size_t)b << 21) + (size_t)((dm >> 8) << 7) + (dm & 255);
        f32x4 v = acc2[nf];
#pragma unroll
        for (int r = 0; r < 4; ++r) {
            int o2 = wv * 16 + (fq << 2) + r;
            float z = fmaxf(v[r] + b2[o2], 0.f);
            out[base + ((size_t)o2 << 14)] = z;
        }
    }
}

// ws layout (bytes):
//   0        hT      fp32 [2][128][128]            131072
//   131072   W3h     fp16 [512][4096]              4194304
//   4325376  W2h     fp16 [128][512]               131072
//   4456448  c0      fp32 [128]                    512
//   4456960  tab     int  [8256] (alloc 16512)     66048
//   21562368 MBt     fp16 [16512][4096]            135266304
extern "C" void kernel_launch(void* const* d_in, const int* in_sizes, int n_in,
                              void* d_out, int out_size, void* d_ws, size_t ws_size,
                              hipStream_t stream) {
    const float* x     = (const float*)d_in[0];
    const float* w_red = (const float*)d_in[1];
    const float* b_red = (const float*)d_in[2];
    const float* w3d   = (const float*)d_in[3];
    const float* b3d   = (const float*)d_in[4];
    const float* w2d   = (const float*)d_in[5];
    const float* b2d   = (const float*)d_in[6];
    float* out = (float*)d_out;

    char* ws = (char*)d_ws;
    float* hT  = (float*)(ws + 0);
    u16*   W3h = (u16*)(ws + 131072);
    u16*   W2h = (u16*)(ws + 4325376);
    float* c0  = (float*)(ws + 4456448);
    int*   tab = (int*)(ws + 4456960);
    u16*   MBt = (u16*)(ws + 21562368);

    conv_kernel<<<dim3(128, 2), 128, 0, stream>>>(x, w_red, b_red, hT);
    prep_kernel<<<257, 256, 0, stream>>>(w2d, b3d, b2d, tab, W2h, c0);
    cvt_kernel<<<8192, 256, 0, stream>>>(w3d, W3h, 2097152);
    mb_build<<<2064, 256, 0, stream>>>(hT, tab, MBt);
    mega_kernel<<<258, 512, 0, stream>>>(W3h, MBt, W2h, b3d, b2d, tab, out);
    fill_kernel<<<dim3(128, 2), 256, 0, stream>>>(c0, out);
}